// Round 1
// baseline (45.442 us; speedup 1.0000x reference)
//
#include <hip/hip_runtime.h>
#include <math.h>

// Effective math (cross-attn K/V are broadcast-identical per batch row, so
// softmax is uniform and ctx == v: the whole self-attn + QK paths are dead):
//   x   = im_repr @ ca_wv + ca_bv                  [256,768]
//   h   = gelu(x @ fi_w1 + fi_b1)  (exact erf)     [256,256]
//   y   = x + h @ fi_w2 + fi_b2                    [256,768]
//   out = LN(y) * ln_g + ln_b

#define BATCH   256
#define DMODEL  768
#define ENCD    128
#define HID     256
#define ROWS    4      // batch rows per block
#define THREADS 256
#define DPT     3      // DMODEL / THREADS

__global__ __launch_bounds__(THREADS) void qf_fused(
    const float* __restrict__ im,    // [256,128]
    const float* __restrict__ wv,    // [128,768]
    const float* __restrict__ bv,    // [768]
    const float* __restrict__ w1,    // [768,256]
    const float* __restrict__ b1,    // [256]
    const float* __restrict__ w2,    // [256,768]
    const float* __restrict__ b2,    // [768]
    const float* __restrict__ gam,   // [768]
    const float* __restrict__ bet,   // [768]
    float* __restrict__ out)         // [256,768]
{
    __shared__ float im_s[ROWS][ENCD];
    __shared__ float x_s[ROWS][DMODEL];
    __shared__ float h1_s[ROWS][HID];
    __shared__ float red_s[4][2 * ROWS];

    const int t  = threadIdx.x;
    const int b0 = blockIdx.x * ROWS;

    // ---- load im rows into LDS ----
    for (int i = t; i < ROWS * ENCD; i += THREADS) {
        int r = i / ENCD, e = i % ENCD;
        im_s[r][e] = im[(b0 + r) * ENCD + e];
    }
    __syncthreads();

    // ---- phase 1: x = im @ wv + bv ----
    float xr[ROWS][DPT];
    {
        float acc[ROWS][DPT];
        #pragma unroll
        for (int r = 0; r < ROWS; ++r)
            #pragma unroll
            for (int i = 0; i < DPT; ++i) acc[r][i] = 0.f;

        #pragma unroll 8
        for (int e = 0; e < ENCD; ++e) {
            float w[DPT];
            #pragma unroll
            for (int i = 0; i < DPT; ++i) w[i] = wv[e * DMODEL + t + i * THREADS];
            #pragma unroll
            for (int r = 0; r < ROWS; ++r) {
                float iv = im_s[r][e];
                #pragma unroll
                for (int i = 0; i < DPT; ++i) acc[r][i] += iv * w[i];
            }
        }
        #pragma unroll
        for (int r = 0; r < ROWS; ++r)
            #pragma unroll
            for (int i = 0; i < DPT; ++i) {
                xr[r][i] = acc[r][i] + bv[t + i * THREADS];
                x_s[r][t + i * THREADS] = xr[r][i];
            }
    }
    __syncthreads();

    // ---- phase 2: h1 = gelu(x @ w1 + b1), thread t owns column j = t ----
    {
        float h[ROWS];
        #pragma unroll
        for (int r = 0; r < ROWS; ++r) h[r] = b1[t];

        #pragma unroll 8
        for (int d = 0; d < DMODEL; ++d) {
            float w = w1[d * HID + t];
            #pragma unroll
            for (int r = 0; r < ROWS; ++r) h[r] += x_s[r][d] * w;
        }
        #pragma unroll
        for (int r = 0; r < ROWS; ++r) {
            float v = h[r];
            h1_s[r][t] = 0.5f * v * (1.f + erff(v * 0.70710678118654752f));
        }
    }
    __syncthreads();

    // ---- phase 3: y = x + h1 @ w2 + b2 ----
    float y[ROWS][DPT];
    {
        float acc[ROWS][DPT];
        #pragma unroll
        for (int r = 0; r < ROWS; ++r)
            #pragma unroll
            for (int i = 0; i < DPT; ++i) acc[r][i] = b2[t + i * THREADS];

        #pragma unroll 8
        for (int j = 0; j < HID; ++j) {
            float w[DPT];
            #pragma unroll
            for (int i = 0; i < DPT; ++i) w[i] = w2[j * DMODEL + t + i * THREADS];
            #pragma unroll
            for (int r = 0; r < ROWS; ++r) {
                float hv = h1_s[r][j];
                #pragma unroll
                for (int i = 0; i < DPT; ++i) acc[r][i] += hv * w[i];
            }
        }
        #pragma unroll
        for (int r = 0; r < ROWS; ++r)
            #pragma unroll
            for (int i = 0; i < DPT; ++i) y[r][i] = xr[r][i] + acc[r][i];
    }

    // ---- phase 4: LayerNorm per row ----
    float s[ROWS], q[ROWS];
    #pragma unroll
    for (int r = 0; r < ROWS; ++r) {
        s[r] = 0.f; q[r] = 0.f;
        #pragma unroll
        for (int i = 0; i < DPT; ++i) { s[r] += y[r][i]; q[r] += y[r][i] * y[r][i]; }
    }
    const int lane = t & 63, wave = t >> 6;
    #pragma unroll
    for (int off = 32; off > 0; off >>= 1) {
        #pragma unroll
        for (int r = 0; r < ROWS; ++r) {
            s[r] += __shfl_down(s[r], off);
            q[r] += __shfl_down(q[r], off);
        }
    }
    if (lane == 0) {
        #pragma unroll
        for (int r = 0; r < ROWS; ++r) {
            red_s[wave][r] = s[r];
            red_s[wave][ROWS + r] = q[r];
        }
    }
    __syncthreads();

    float mu[ROWS], rstd[ROWS];
    #pragma unroll
    for (int r = 0; r < ROWS; ++r) {
        float ss = 0.f, qq = 0.f;
        #pragma unroll
        for (int w = 0; w < 4; ++w) { ss += red_s[w][r]; qq += red_s[w][ROWS + r]; }
        mu[r] = ss * (1.f / DMODEL);
        float var = qq * (1.f / DMODEL) - mu[r] * mu[r];
        rstd[r] = rsqrtf(var + 1e-12f);
    }

    #pragma unroll
    for (int r = 0; r < ROWS; ++r)
        #pragma unroll
        for (int i = 0; i < DPT; ++i) {
            int d = t + i * THREADS;
            out[(b0 + r) * DMODEL + d] =
                (y[r][i] - mu[r]) * rstd[r] * gam[d] + bet[d];
        }
}

extern "C" void kernel_launch(void* const* d_in, const int* in_sizes, int n_in,
                              void* d_out, int out_size, void* d_ws, size_t ws_size,
                              hipStream_t stream) {
    const float* im  = (const float*)d_in[0];   // im_repr [256,128]
    const float* wv  = (const float*)d_in[13];  // ca_wv   [128,768]
    const float* bv  = (const float*)d_in[14];  // ca_bv   [768]
    const float* w1  = (const float*)d_in[16];  // fi_w1   [768,256]
    const float* b1  = (const float*)d_in[17];  // fi_b1   [256]
    const float* w2  = (const float*)d_in[18];  // fi_w2   [256,768]
    const float* b2  = (const float*)d_in[19];  // fi_b2   [768]
    const float* g   = (const float*)d_in[20];  // ln_g    [768]
    const float* bt  = (const float*)d_in[21];  // ln_b    [768]
    float* out = (float*)d_out;

    dim3 grid(BATCH / ROWS), block(THREADS);
    qf_fused<<<grid, block, 0, stream>>>(im, wv, bv, w1, b1, w2, b2, g, bt, out);
}

// Round 2
// 38.400 us; speedup vs baseline: 1.1834x; 1.1834x over previous
//
#include <hip/hip_runtime.h>
#include <math.h>

// Effective math (cross-attn K/V rows are identical per batch element ->
// softmax uniform -> ctx == v; self-attn and QK paths are dead):
//   x   = im_repr @ ca_wv + ca_bv                  [256,768]
//   h   = gelu(x @ fi_w1 + fi_b1)  (exact erf)     [256,256]
//   y   = x + h @ fi_w2 + fi_b2                    [256,768]
//   out = LN(y) * ln_g + ln_b
//
// Round-1 restructure: 3 kernels, K-split + row-grouped for latency hiding.

#define DMODEL  768
#define ENCD    128
#define HID     256
#define R       4        // rows per block

// ws layout (floats)
#define WS_X    0                      // x  [256][768]
#define WS_P    (256 * 768)            // p  [3][256][256]

// ---------------- K1: x = im @ wv + bv ----------------
// grid (3 coltiles, 64 rowgroups), 256 threads; col = ct*256+t
__global__ __launch_bounds__(256) void k1_x(
    const float* __restrict__ im,   // [256,128]
    const float* __restrict__ wv,   // [128,768]
    const float* __restrict__ bv,   // [768]
    float* __restrict__ ws)
{
    __shared__ float im_s[R][ENCD];
    const int t  = threadIdx.x;
    const int ct = blockIdx.x;
    const int r0 = blockIdx.y * R;
    const int col = ct * 256 + t;

    #pragma unroll
    for (int it = 0; it < 2; ++it) {
        int idx = t + it * 256;           // 512 total
        im_s[idx >> 7][idx & 127] = im[(r0 + (idx >> 7)) * ENCD + (idx & 127)];
    }
    __syncthreads();

    float acc[R] = {0.f, 0.f, 0.f, 0.f};
    #pragma unroll 8
    for (int e = 0; e < ENCD; ++e) {
        float w = wv[e * DMODEL + col];
        #pragma unroll
        for (int r = 0; r < R; ++r) acc[r] += im_s[r][e] * w;
    }
    float b = bv[col];
    float* x = ws + WS_X;
    #pragma unroll
    for (int r = 0; r < R; ++r) x[(r0 + r) * DMODEL + col] = acc[r] + b;
}

// ---------------- K2: p[kc] = x[:, kc*256:+256] @ w1[kc*256:+256, :] ----------------
// grid (3 kchunks, 64 rowgroups), 256 threads; output col = t
__global__ __launch_bounds__(256) void k2_partial(
    const float* __restrict__ w1,   // [768,256]
    float* __restrict__ ws)
{
    __shared__ float x_s[R][256];
    const int t  = threadIdx.x;
    const int kc = blockIdx.x;
    const int r0 = blockIdx.y * R;
    const float* x = ws + WS_X;

    #pragma unroll
    for (int r = 0; r < R; ++r)
        x_s[r][t] = x[(r0 + r) * DMODEL + kc * 256 + t];
    __syncthreads();

    float acc[R] = {0.f, 0.f, 0.f, 0.f};
    const float* w1c = w1 + kc * 256 * HID;
    #pragma unroll 8
    for (int k = 0; k < 256; ++k) {
        float w = w1c[k * HID + t];
        #pragma unroll
        for (int r = 0; r < R; ++r) acc[r] += x_s[r][k] * w;
    }
    float* p = ws + WS_P + kc * (256 * HID);
    #pragma unroll
    for (int r = 0; r < R; ++r) p[(r0 + r) * HID + t] = acc[r];
}

// ---------------- K3: h = gelu(sum p + b1); y = x + h@w2 + b2; out = LN(y) ----------------
// grid 64 rowgroups, 192 threads; thread t owns cols 4t..4t+3
__global__ __launch_bounds__(192) void k3_out(
    const float* __restrict__ b1,   // [256]
    const float* __restrict__ w2,   // [256,768]
    const float* __restrict__ b2,   // [768]
    const float* __restrict__ gam,  // [768]
    const float* __restrict__ bet,  // [768]
    const float* __restrict__ ws_c,
    float* __restrict__ out)
{
    __shared__ float h_s[R][HID];
    __shared__ float red_s[3][2 * R];
    const int t  = threadIdx.x;
    const int r0 = blockIdx.x * R;
    const float* x = ws_c + WS_X;
    const float* p0 = ws_c + WS_P;
    const float* p1 = p0 + 256 * HID;
    const float* p2 = p1 + 256 * HID;

    // h = gelu(p0+p1+p2+b1)  (R*256 = 1024 elems over 192 threads)
    for (int i = t; i < R * HID; i += 192) {
        int r = i >> 8, j = i & 255;
        int o = (r0 + r) * HID + j;
        float v = p0[o] + p1[o] + p2[o] + b1[j];
        h_s[r][j] = 0.5f * v * (1.f + erff(v * 0.70710678118654752f));
    }
    __syncthreads();

    // y = x + h @ w2 + b2  (float4 over cols)
    const int c0 = 4 * t;
    float4 acc[R];
    {
        float4 bb = *(const float4*)(b2 + c0);
        #pragma unroll
        for (int r = 0; r < R; ++r) acc[r] = bb;
    }
    #pragma unroll 8
    for (int j = 0; j < HID; ++j) {
        float4 w = *(const float4*)(w2 + j * DMODEL + c0);
        #pragma unroll
        for (int r = 0; r < R; ++r) {
            float hv = h_s[r][j];
            acc[r].x += hv * w.x; acc[r].y += hv * w.y;
            acc[r].z += hv * w.z; acc[r].w += hv * w.w;
        }
    }
    float y[R][4];
    #pragma unroll
    for (int r = 0; r < R; ++r) {
        float4 xv = *(const float4*)(x + (r0 + r) * DMODEL + c0);
        y[r][0] = xv.x + acc[r].x; y[r][1] = xv.y + acc[r].y;
        y[r][2] = xv.z + acc[r].z; y[r][3] = xv.w + acc[r].w;
    }

    // LayerNorm reduce (768 vals per row over 192 threads)
    float s[R], q[R];
    #pragma unroll
    for (int r = 0; r < R; ++r) {
        s[r] = 0.f; q[r] = 0.f;
        #pragma unroll
        for (int c = 0; c < 4; ++c) { s[r] += y[r][c]; q[r] += y[r][c] * y[r][c]; }
    }
    const int lane = t & 63, wave = t >> 6;
    #pragma unroll
    for (int off = 32; off > 0; off >>= 1) {
        #pragma unroll
        for (int r = 0; r < R; ++r) {
            s[r] += __shfl_down(s[r], off);
            q[r] += __shfl_down(q[r], off);
        }
    }
    if (lane == 0) {
        #pragma unroll
        for (int r = 0; r < R; ++r) { red_s[wave][r] = s[r]; red_s[wave][R + r] = q[r]; }
    }
    __syncthreads();

    float mu[R], rstd[R];
    #pragma unroll
    for (int r = 0; r < R; ++r) {
        float ss = 0.f, qq = 0.f;
        #pragma unroll
        for (int w = 0; w < 3; ++w) { ss += red_s[w][r]; qq += red_s[w][R + r]; }
        mu[r] = ss * (1.f / DMODEL);
        float var = qq * (1.f / DMODEL) - mu[r] * mu[r];
        rstd[r] = rsqrtf(var + 1e-12f);
    }

    float4 gv = *(const float4*)(gam + c0);
    float4 bv = *(const float4*)(bet + c0);
    #pragma unroll
    for (int r = 0; r < R; ++r) {
        float4 o;
        o.x = (y[r][0] - mu[r]) * rstd[r] * gv.x + bv.x;
        o.y = (y[r][1] - mu[r]) * rstd[r] * gv.y + bv.y;
        o.z = (y[r][2] - mu[r]) * rstd[r] * gv.z + bv.z;
        o.w = (y[r][3] - mu[r]) * rstd[r] * gv.w + bv.w;
        *(float4*)(out + (r0 + r) * DMODEL + c0) = o;
    }
}

extern "C" void kernel_launch(void* const* d_in, const int* in_sizes, int n_in,
                              void* d_out, int out_size, void* d_ws, size_t ws_size,
                              hipStream_t stream) {
    const float* im  = (const float*)d_in[0];   // im_repr [256,128]
    const float* wv  = (const float*)d_in[13];  // ca_wv   [128,768]
    const float* bv  = (const float*)d_in[14];  // ca_bv   [768]
    const float* w1  = (const float*)d_in[16];  // fi_w1   [768,256]
    const float* b1  = (const float*)d_in[17];  // fi_b1   [256]
    const float* w2  = (const float*)d_in[18];  // fi_w2   [256,768]
    const float* b2  = (const float*)d_in[19];  // fi_b2   [768]
    const float* g   = (const float*)d_in[20];  // ln_g    [768]
    const float* bt  = (const float*)d_in[21];  // ln_b    [768]
    float* out = (float*)d_out;
    float* ws  = (float*)d_ws;

    k1_x<<<dim3(3, 64), 256, 0, stream>>>(im, wv, bv, ws);
    k2_partial<<<dim3(3, 64), 256, 0, stream>>>(w1, ws);
    k3_out<<<dim3(64), 192, 0, stream>>>(b1, w2, b2, g, bt, ws, out);
}

// Round 3
// 28.911 us; speedup vs baseline: 1.5718x; 1.3282x over previous
//
#include <hip/hip_runtime.h>
#include <math.h>

// Effective math (cross-attn K/V rows identical per batch element ->
// softmax uniform -> ctx == v; self-attn and QK paths are dead):
//   x   = im_repr @ ca_wv + ca_bv                  [256,768]
//   h   = gelu(x @ fi_w1 + fi_b1)  (exact erf)     [256,256]
//   y   = x + h @ fi_w2 + fi_b2                    [256,768]
//   out = LN(y) * ln_g + ln_b
//
// Round-2: 4 kernels, every stage >=256 blocks for latency hiding.

#define DMODEL  768
#define ENCD    128
#define HID     256
#define R2      2

// ws layout (floats)
#define WS_X    0                       // x  [256][768]
#define WS_P    (256 * 768)             // p  [3][256][256]
#define WS_Y    (WS_P + 3 * 256 * 256)  // y  [256][768]

__device__ __forceinline__ float gelu_exact(float v) {
    return 0.5f * v * (1.f + erff(v * 0.70710678118654752f));
}

// ---- k1: x = im @ wv + bv.  grid(3 coltiles, 128 rowpairs), 256 thr ----
__global__ __launch_bounds__(256) void k1_x(
    const float* __restrict__ im, const float* __restrict__ wv,
    const float* __restrict__ bv, float* __restrict__ ws)
{
    __shared__ float im_s[R2][ENCD];
    const int t = threadIdx.x, ct = blockIdx.x, r0 = blockIdx.y * R2;
    im_s[t >> 7][t & 127] = im[(r0 + (t >> 7)) * ENCD + (t & 127)];
    __syncthreads();

    const int col = ct * 256 + t;
    float a0 = 0.f, a1 = 0.f;
    #pragma unroll 8
    for (int e = 0; e < ENCD; ++e) {
        float w = wv[e * DMODEL + col];
        a0 += im_s[0][e] * w;
        a1 += im_s[1][e] * w;
    }
    float b = bv[col];
    float* x = ws + WS_X;
    x[(r0 + 0) * DMODEL + col] = a0 + b;
    x[(r0 + 1) * DMODEL + col] = a1 + b;
}

// ---- k2: p[kc] = x[:,kc*256:+256] @ w1[kc*256:+256,:]. grid(3,128), 256 thr ----
__global__ __launch_bounds__(256) void k2_partial(
    const float* __restrict__ w1, float* __restrict__ ws)
{
    __shared__ float x_s[R2][256];
    const int t = threadIdx.x, kc = blockIdx.x, r0 = blockIdx.y * R2;
    const float* x = ws + WS_X;
    x_s[0][t] = x[(r0 + 0) * DMODEL + kc * 256 + t];
    x_s[1][t] = x[(r0 + 1) * DMODEL + kc * 256 + t];
    __syncthreads();

    float a0 = 0.f, a1 = 0.f;
    const float* w1c = w1 + kc * 256 * HID;
    #pragma unroll 8
    for (int k = 0; k < 256; ++k) {
        float w = w1c[k * HID + t];
        a0 += x_s[0][k] * w;
        a1 += x_s[1][k] * w;
    }
    float* p = ws + WS_P + kc * (256 * HID);
    p[(r0 + 0) * HID + t] = a0;
    p[(r0 + 1) * HID + t] = a1;
}

// ---- k3: y = x + gelu(sum p + b1) @ w2 + b2. grid(3,128), 256 thr ----
__global__ __launch_bounds__(256) void k3_y(
    const float* __restrict__ b1, const float* __restrict__ w2,
    const float* __restrict__ b2, float* __restrict__ ws)
{
    __shared__ float h_s[R2][HID];
    const int t = threadIdx.x, ct = blockIdx.x, r0 = blockIdx.y * R2;
    const float* p0 = ws + WS_P;
    const float* p1 = p0 + 256 * HID;
    const float* p2 = p1 + 256 * HID;

    #pragma unroll
    for (int i = 0; i < R2; ++i) {
        int o = (r0 + i) * HID + t;
        h_s[i][t] = gelu_exact(p0[o] + p1[o] + p2[o] + b1[t]);
    }
    __syncthreads();

    const int col = ct * 256 + t;
    float a0 = b2[col], a1 = a0;
    #pragma unroll 8
    for (int j = 0; j < HID; ++j) {
        float w = w2[j * DMODEL + col];
        a0 += h_s[0][j] * w;
        a1 += h_s[1][j] * w;
    }
    const float* x = ws + WS_X;
    float* y = ws + WS_Y;
    y[(r0 + 0) * DMODEL + col] = x[(r0 + 0) * DMODEL + col] + a0;
    y[(r0 + 1) * DMODEL + col] = x[(r0 + 1) * DMODEL + col] + a1;
}

// ---- k4: out = LN(y)*g + b. grid(256 rows), 256 thr ----
__global__ __launch_bounds__(256) void k4_ln(
    const float* __restrict__ gam, const float* __restrict__ bet,
    const float* __restrict__ ws, float* __restrict__ out)
{
    __shared__ float red[4][2];
    const int t = threadIdx.x, r = blockIdx.x;
    const float* y = ws + WS_Y + r * DMODEL;

    float v0 = y[t], v1 = y[t + 256], v2 = y[t + 512];
    float s = v0 + v1 + v2;
    float q = v0 * v0 + v1 * v1 + v2 * v2;
    #pragma unroll
    for (int off = 32; off > 0; off >>= 1) {
        s += __shfl_down(s, off);
        q += __shfl_down(q, off);
    }
    const int lane = t & 63, wave = t >> 6;
    if (lane == 0) { red[wave][0] = s; red[wave][1] = q; }
    __syncthreads();
    float ss = red[0][0] + red[1][0] + red[2][0] + red[3][0];
    float qq = red[0][1] + red[1][1] + red[2][1] + red[3][1];
    float mu = ss * (1.f / DMODEL);
    float rstd = rsqrtf(qq * (1.f / DMODEL) - mu * mu + 1e-12f);

    out[r * DMODEL + t]       = (v0 - mu) * rstd * gam[t]       + bet[t];
    out[r * DMODEL + t + 256] = (v1 - mu) * rstd * gam[t + 256] + bet[t + 256];
    out[r * DMODEL + t + 512] = (v2 - mu) * rstd * gam[t + 512] + bet[t + 512];
}

extern "C" void kernel_launch(void* const* d_in, const int* in_sizes, int n_in,
                              void* d_out, int out_size, void* d_ws, size_t ws_size,
                              hipStream_t stream) {
    const float* im  = (const float*)d_in[0];   // im_repr [256,128]
    const float* wv  = (const float*)d_in[13];  // ca_wv   [128,768]
    const float* bv  = (const float*)d_in[14];  // ca_bv   [768]
    const float* w1  = (const float*)d_in[16];  // fi_w1   [768,256]
    const float* b1  = (const float*)d_in[17];  // fi_b1   [256]
    const float* w2  = (const float*)d_in[18];  // fi_w2   [256,768]
    const float* b2  = (const float*)d_in[19];  // fi_b2   [768]
    const float* g   = (const float*)d_in[20];  // ln_g    [768]
    const float* bt  = (const float*)d_in[21];  // ln_b    [768]
    float* out = (float*)d_out;
    float* ws  = (float*)d_ws;

    k1_x     <<<dim3(3, 128), 256, 0, stream>>>(im, wv, bv, ws);
    k2_partial<<<dim3(3, 128), 256, 0, stream>>>(w1, ws);
    k3_y     <<<dim3(3, 128), 256, 0, stream>>>(b1, w2, b2, ws);
    k4_ln    <<<dim3(256), 256, 0, stream>>>(g, bt, ws, out);
}